// Round 8
// baseline (16969.678 us; speedup 1.0000x reference)
//
#include <hip/hip_runtime.h>
#include <stdint.h>

#define B_   128
#define T_   64
#define V_   1024
#define TS_  64
#define H_   512
#define K_   (V_ + TS_)   // 1088

// ---------------------------------------------------------------------------
// Fused time-aware GRU scan, round 8.
//
// Structure identical to round 6 (8.97ms PASS): 64 WGs x 256 threads
// (4 waves), wave q = blk*4+w owns h[2q],h[2q+1]; wave 0 of each WG also
// polls and broadcasts h via LDS + one __syncthreads.
//
// Evidence so far: pollers 256->64 gave only 1.27x; backoff+dedicated
// poller (r7) was -7%. The ~2.2us/step fixed term is NOT sweep-rate
// congestion. New target: same-line LLC service serialization -- r6
// leaders re-sweep ALL 64 lines every retry although only a few words are
// stale, so the laggard lines (exactly where producers must land their
// stores) eat ~64 redundant reads per sweep generation.
//
// r8 changes (both single-hop; no added chain hops, no sleep -- r7 lesson):
//   1. PENDING-MASK poll: per-lane mask of stale words; retries reload
//      only stale words (exec-masked loads). First sweep == r6 sweep;
//      retry traffic drops ~10x.
//   2. REPLICATED h-buf x2: producer lanes 0..3 store the 2 tagged words
//      into 2 replicas (parallel stores, off critical path); even/odd WGs
//      poll different replicas -> same-line sharers halved.
//
// Safety induction unchanged from r6 (tag v+1 only stored after sync(v),
// which needs leader to have observed all tags v; slot (v+1)&1 was last
// read for v-1 => overwrite race-free). Bounded spin watchdog (2^21)
// turns protocol bugs into fast absmax-fails instead of dead containers.
//
// Masked steps (t >= lens[b]) skipped; chain = sum(lens) ~ 4032 steps.
// Workspace: 2 replicas x 2 slots x 512 x u64 = 16KB. Poison tag
// 0xAAAAAAAA != any ver (< 8200).
// ---------------------------------------------------------------------------

__device__ __forceinline__ float sigmoidf_(float x) {
    return 1.0f / (1.0f + __expf(-x));
}
__device__ __forceinline__ float tanhf_(float x) {
    x = fminf(fmaxf(x, -15.0f), 15.0f);
    const float e = __expf(2.0f * x);
    return (e - 1.0f) / (e + 1.0f);
}

__global__ __launch_bounds__(256, 1) void gru_fused(
    const float* __restrict__ visit_emb, const float* __restrict__ intervals,
    const float* __restrict__ W_time, const float* __restrict__ b_time,
    const float* __restrict__ W_ih, const float* __restrict__ W_hh,
    const float* __restrict__ b_ih, const float* __restrict__ b_hh,
    const int* __restrict__ lens,
    uint64_t* h_buf /* [2 replica][2 slot][H_] tagged */,
    float* __restrict__ out)
{
    const int lane = threadIdx.x & 63;
    const int wave = threadIdx.x >> 6;        // 0..3
    const int q    = blockIdx.x * 4 + wave;   // 0..255 global wave id
    const int j0   = q * 2;
    const int j1   = j0 + 1;
    const int rep  = blockIdx.x & 1;          // which replica this WG polls

    __shared__ float hs[H_];                  // per-WG broadcast of h

    // ---- register-resident W_hh rows (k = lane + 64u) -------------------
    float wr0[8], wr1[8], wz0[8], wz1[8], wn0[8], wn1[8];
    #pragma unroll
    for (int u = 0; u < 8; ++u) {
        const int k = lane + 64 * u;
        wr0[u] = W_hh[(size_t)j0 * H_ + k];
        wr1[u] = W_hh[(size_t)j1 * H_ + k];
        wz0[u] = W_hh[(size_t)(H_ + j0) * H_ + k];
        wz1[u] = W_hh[(size_t)(H_ + j1) * H_ + k];
        wn0[u] = W_hh[(size_t)(2 * H_ + j0) * H_ + k];
        wn1[u] = W_hh[(size_t)(2 * H_ + j1) * H_ + k];
    }
    // ---- W_ih rows: u<16 visit part, u==16 time part --------------------
    float ir0[17], ir1[17], iz0[17], iz1[17], in0[17], in1[17];
    #pragma unroll
    for (int u = 0; u < 16; ++u) {
        const int k = lane + 64 * u;
        ir0[u] = W_ih[(size_t)j0 * K_ + k];
        ir1[u] = W_ih[(size_t)j1 * K_ + k];
        iz0[u] = W_ih[(size_t)(H_ + j0) * K_ + k];
        iz1[u] = W_ih[(size_t)(H_ + j1) * K_ + k];
        in0[u] = W_ih[(size_t)(2 * H_ + j0) * K_ + k];
        in1[u] = W_ih[(size_t)(2 * H_ + j1) * K_ + k];
    }
    ir0[16] = W_ih[(size_t)j0 * K_ + V_ + lane];
    ir1[16] = W_ih[(size_t)j1 * K_ + V_ + lane];
    iz0[16] = W_ih[(size_t)(H_ + j0) * K_ + V_ + lane];
    iz1[16] = W_ih[(size_t)(H_ + j1) * K_ + V_ + lane];
    in0[16] = W_ih[(size_t)(2 * H_ + j0) * K_ + V_ + lane];
    in1[16] = W_ih[(size_t)(2 * H_ + j1) * K_ + V_ + lane];

    const float wt = W_time[lane];
    const float bt = b_time[lane];

    const float bir0 = b_ih[j0],          bir1 = b_ih[j1];
    const float biz0 = b_ih[H_ + j0],     biz1 = b_ih[H_ + j1];
    const float bin0 = b_ih[2 * H_ + j0], bin1 = b_ih[2 * H_ + j1];
    const float bhr0 = b_hh[j0],          bhr1 = b_hh[j1];
    const float bhz0 = b_hh[H_ + j0],     bhz1 = b_hh[H_ + j1];
    const float bhn0 = b_hh[2 * H_ + j0], bhn1 = b_hh[2 * H_ + j1];

    float hj0 = 0.0f, hj1 = 0.0f;
    uint32_t ver  = 1;    // ver 1 == initial zero state, lives in slot 1
    uint32_t dead = 0;    // leader watchdog state (wave-uniform)

    // publish initial tagged state to both replicas (lanes 0..3)
    if (lane < 4)
        __hip_atomic_store(
            &h_buf[(size_t)(lane >> 1) * 1024 + (ver & 1) * H_ + j0 + (lane & 1)],
            (uint64_t)ver << 32,
            __ATOMIC_RELAXED, __HIP_MEMORY_SCOPE_AGENT);

    float xv[16];     // current step's visit row (prefetched)
    float iv = 0.0f;  // current step's interval

    for (int b = 0; b < B_; ++b) {
        const int L = lens[b];
        if (L > 0) {
            iv = intervals[b * T_];
            const float* vrow = visit_emb + (size_t)(b * T_) * V_;
            #pragma unroll
            for (int u = 0; u < 16; ++u) xv[u] = vrow[lane + 64 * u];
        }
        for (int t = 0; t < L; ++t) {
            // ---- x-side dots from prefetched row (h-independent) --------
            const float xt = fmaf(iv, wt, bt);
            float ar0 = ir0[16] * xt, ar1 = ir1[16] * xt;
            float az0 = iz0[16] * xt, az1 = iz1[16] * xt;
            float xn0 = in0[16] * xt, xn1 = in1[16] * xt;
            #pragma unroll
            for (int u = 0; u < 16; ++u) {
                ar0 = fmaf(ir0[u], xv[u], ar0);
                ar1 = fmaf(ir1[u], xv[u], ar1);
                az0 = fmaf(iz0[u], xv[u], az0);
                az1 = fmaf(iz1[u], xv[u], az1);
                xn0 = fmaf(in0[u], xv[u], xn0);
                xn1 = fmaf(in1[u], xv[u], xn1);
            }
            // ---- prefetch next step's x row (hides under the poll) ------
            if (t + 1 < L) {
                iv = intervals[b * T_ + t + 1];
                const float* vrow = visit_emb + (size_t)(b * T_ + t + 1) * V_;
                #pragma unroll
                for (int u = 0; u < 16; ++u) xv[u] = vrow[lane + 64 * u];
            }

            // ---- leader wave: pending-mask poll, broadcast via LDS ------
            if (wave == 0) {
                const uint64_t* src =
                    h_buf + (size_t)rep * 1024 + (ver & 1) * H_;
                uint64_t w[8];
                if (!dead) {
                    uint32_t pend  = 0xFFu;
                    uint32_t tries = 0;
                    for (;;) {
                        #pragma unroll
                        for (int u = 0; u < 8; ++u) {
                            if (pend & (1u << u)) {
                                const uint64_t x = __hip_atomic_load(
                                    &src[lane + 64 * u],
                                    __ATOMIC_RELAXED,
                                    __HIP_MEMORY_SCOPE_AGENT);
                                if ((uint32_t)(x >> 32) == ver) {
                                    w[u] = x;
                                    pend &= ~(1u << u);
                                }
                            }
                        }
                        if (__all(pend == 0)) break;
                        if (++tries > (1u << 21)) { dead = 1; break; }
                    }
                }
                if (dead) {
                    // watchdog tripped: free-run with one unchecked sweep
                    #pragma unroll
                    for (int u = 0; u < 8; ++u)
                        w[u] = __hip_atomic_load(&src[lane + 64 * u],
                                                 __ATOMIC_RELAXED,
                                                 __HIP_MEMORY_SCOPE_AGENT);
                }
                #pragma unroll
                for (int u = 0; u < 8; ++u)
                    hs[lane + 64 * u] = __uint_as_float((uint32_t)w[u]);
            }
            __syncthreads();

            float h[8];
            #pragma unroll
            for (int u = 0; u < 8; ++u) h[u] = hs[lane + 64 * u];

            // ---- h-side dots; r/z merged with x-side, n kept split ------
            float hn0 = 0.0f, hn1 = 0.0f;
            #pragma unroll
            for (int u = 0; u < 8; ++u) {
                ar0 = fmaf(wr0[u], h[u], ar0);
                ar1 = fmaf(wr1[u], h[u], ar1);
                az0 = fmaf(wz0[u], h[u], az0);
                az1 = fmaf(wz1[u], h[u], az1);
                hn0 = fmaf(wn0[u], h[u], hn0);
                hn1 = fmaf(wn1[u], h[u], hn1);
            }
            #pragma unroll
            for (int m = 1; m < 64; m <<= 1) {
                ar0 += __shfl_xor(ar0, m, 64);
                ar1 += __shfl_xor(ar1, m, 64);
                az0 += __shfl_xor(az0, m, 64);
                az1 += __shfl_xor(az1, m, 64);
                xn0 += __shfl_xor(xn0, m, 64);
                xn1 += __shfl_xor(xn1, m, 64);
                hn0 += __shfl_xor(hn0, m, 64);
                hn1 += __shfl_xor(hn1, m, 64);
            }

            const float r0 = sigmoidf_(ar0 + bir0 + bhr0);
            const float r1 = sigmoidf_(ar1 + bir1 + bhr1);
            const float z0 = sigmoidf_(az0 + biz0 + bhz0);
            const float z1 = sigmoidf_(az1 + biz1 + bhz1);
            const float n0 = tanhf_(xn0 + bin0 + r0 * (hn0 + bhn0));
            const float n1 = tanhf_(xn1 + bin1 + r1 * (hn1 + bhn1));
            hj0 = (1.0f - z0) * n0 + z0 * hj0;
            hj1 = (1.0f - z1) * n1 + z1 * hj1;

            // ---- publish tagged h(ver+1) to both replicas ---------------
            ++ver;
            const float hv = ((lane & 1) == 0) ? hj0 : hj1;
            if (lane < 4)
                __hip_atomic_store(
                    &h_buf[(size_t)(lane >> 1) * 1024 + (ver & 1) * H_
                           + j0 + (lane & 1)],
                    ((uint64_t)ver << 32) | (uint64_t)__float_as_uint(hv),
                    __ATOMIC_RELAXED, __HIP_MEMORY_SCOPE_AGENT);
        }
        // out[b] = h after sample b's (possibly empty) segment
        if (lane < 2) out[b * H_ + j0 + lane] = (lane == 0) ? hj0 : hj1;
    }
}

// ---------------------------------------------------------------------------
extern "C" void kernel_launch(void* const* d_in, const int* in_sizes, int n_in,
                              void* d_out, int out_size, void* d_ws, size_t ws_size,
                              hipStream_t stream)
{
    const float* visit_emb = (const float*)d_in[0];
    const float* intervals = (const float*)d_in[1];
    const float* W_time    = (const float*)d_in[2];
    const float* b_time    = (const float*)d_in[3];
    const float* W_ih      = (const float*)d_in[4];
    const float* W_hh      = (const float*)d_in[5];
    const float* b_ih      = (const float*)d_in[6];
    const float* b_hh      = (const float*)d_in[7];
    const int*   lens      = (const int*)d_in[8];
    float*       out       = (float*)d_out;

    // workspace: 2 replicas x 2 slots x 512 x u64 = 16 KiB
    uint64_t* h_buf = (uint64_t*)d_ws;

    gru_fused<<<64, 256, 0, stream>>>(visit_emb, intervals, W_time, b_time,
                                      W_ih, W_hh, b_ih, b_hh, lens, h_buf, out);
}

// Round 9
// 8601.864 us; speedup vs baseline: 1.9728x; 1.9728x over previous
//
#include <hip/hip_runtime.h>
#include <stdint.h>

#define B_   128
#define T_   64
#define V_   1024
#define TS_  64
#define H_   512
#define K_   (V_ + TS_)   // 1088

// ---------------------------------------------------------------------------
// Fused time-aware GRU scan, round 9.
//
// Structure = round 6 exactly (best: 8.97ms / 2.23us/step): 64 WGs x 256
// threads (4 waves), wave q = blk*4+w owns h[2q],h[2q+1]; wave 0 polls and
// broadcasts h via LDS + one __syncthreads. Register-resident weights,
// 8-value butterfly.
//
// Evidence ledger: r7 sleep backoff -7%; r8 pending-mask+replicas -89%;
// r2->r6 4x poller cut only +27%. Traffic-reduction knobs never help;
// observation-slowing knobs always hurt => exchange is LATENCY-bound
// (straggler store visibility + sweep observe), not contention-bound.
//
// r9 change (attacks straggler-set size and sweep latency, no new hops):
//   bf16-PACKED exchange: each wave's lane 0 stores ONE tagged u64
//     (ver<<32)|(bf16(hj1)<<16)|bf16(hj0)
//   -> 256 store events/step (was 512); sweep = 4 loads/lane over 256
//   words (was 8 over 512). Leader unpacks to fp32 LDS (float2 writes).
//   Numerics: h quantized to bf16-RN once per step; GRU gating is
//   contractive -> random-walk accumulation ~0.005-0.012 < 1.9e-2 thresh.
//
// Safety induction unchanged from r6: tag v+1 stored only after sync(v);
// sync(v) needs leader observed ALL tags v; any tag v postdates that WG's
// sync(v-1), hence postdates its leader's reads of slot (v+1)&1 for v-1.
// So every leader is done with a slot before any wave overwrites it.
// Bounded-spin watchdog (2^21) turns protocol bugs into fast absmax-fails.
//
// Masked steps (t >= lens[b]) skipped; chain = sum(lens) ~ 4032 steps.
// Workspace: 2 slots x 256 x u64 = 4KB. Poison tag 0xAAAAAAAA != any ver.
// ---------------------------------------------------------------------------

__device__ __forceinline__ float sigmoidf_(float x) {
    return 1.0f / (1.0f + __expf(-x));
}
__device__ __forceinline__ float tanhf_(float x) {
    x = fminf(fmaxf(x, -15.0f), 15.0f);
    const float e = __expf(2.0f * x);
    return (e - 1.0f) / (e + 1.0f);
}
__device__ __forceinline__ uint32_t bf16_rn_(float f) {
    uint32_t u = __float_as_uint(f);
    u += 0x7FFFu + ((u >> 16) & 1u);   // round-to-nearest-even
    return u >> 16;
}
__device__ __forceinline__ float bf16_to_f32_(uint32_t b) {
    return __uint_as_float(b << 16);
}

__global__ __launch_bounds__(256, 1) void gru_fused(
    const float* __restrict__ visit_emb, const float* __restrict__ intervals,
    const float* __restrict__ W_time, const float* __restrict__ b_time,
    const float* __restrict__ W_ih, const float* __restrict__ W_hh,
    const float* __restrict__ b_ih, const float* __restrict__ b_hh,
    const int* __restrict__ lens,
    uint64_t* h_buf /* [2 slot][256] tagged packed */,
    float* __restrict__ out)
{
    const int lane = threadIdx.x & 63;
    const int wave = threadIdx.x >> 6;        // 0..3
    const int q    = blockIdx.x * 4 + wave;   // 0..255 global wave id
    const int j0   = q * 2;
    const int j1   = j0 + 1;

    __shared__ float2 hs2[256];               // unpacked h pairs (fp32)
    float* hs = (float*)hs2;                  // alias: hs[512]

    // ---- register-resident W_hh rows (k = lane + 64u) -------------------
    float wr0[8], wr1[8], wz0[8], wz1[8], wn0[8], wn1[8];
    #pragma unroll
    for (int u = 0; u < 8; ++u) {
        const int k = lane + 64 * u;
        wr0[u] = W_hh[(size_t)j0 * H_ + k];
        wr1[u] = W_hh[(size_t)j1 * H_ + k];
        wz0[u] = W_hh[(size_t)(H_ + j0) * H_ + k];
        wz1[u] = W_hh[(size_t)(H_ + j1) * H_ + k];
        wn0[u] = W_hh[(size_t)(2 * H_ + j0) * H_ + k];
        wn1[u] = W_hh[(size_t)(2 * H_ + j1) * H_ + k];
    }
    // ---- W_ih rows: u<16 visit part, u==16 time part --------------------
    float ir0[17], ir1[17], iz0[17], iz1[17], in0[17], in1[17];
    #pragma unroll
    for (int u = 0; u < 16; ++u) {
        const int k = lane + 64 * u;
        ir0[u] = W_ih[(size_t)j0 * K_ + k];
        ir1[u] = W_ih[(size_t)j1 * K_ + k];
        iz0[u] = W_ih[(size_t)(H_ + j0) * K_ + k];
        iz1[u] = W_ih[(size_t)(H_ + j1) * K_ + k];
        in0[u] = W_ih[(size_t)(2 * H_ + j0) * K_ + k];
        in1[u] = W_ih[(size_t)(2 * H_ + j1) * K_ + k];
    }
    ir0[16] = W_ih[(size_t)j0 * K_ + V_ + lane];
    ir1[16] = W_ih[(size_t)j1 * K_ + V_ + lane];
    iz0[16] = W_ih[(size_t)(H_ + j0) * K_ + V_ + lane];
    iz1[16] = W_ih[(size_t)(H_ + j1) * K_ + V_ + lane];
    in0[16] = W_ih[(size_t)(2 * H_ + j0) * K_ + V_ + lane];
    in1[16] = W_ih[(size_t)(2 * H_ + j1) * K_ + V_ + lane];

    const float wt = W_time[lane];
    const float bt = b_time[lane];

    const float bir0 = b_ih[j0],          bir1 = b_ih[j1];
    const float biz0 = b_ih[H_ + j0],     biz1 = b_ih[H_ + j1];
    const float bin0 = b_ih[2 * H_ + j0], bin1 = b_ih[2 * H_ + j1];
    const float bhr0 = b_hh[j0],          bhr1 = b_hh[j1];
    const float bhz0 = b_hh[H_ + j0],     bhz1 = b_hh[H_ + j1];
    const float bhn0 = b_hh[2 * H_ + j0], bhn1 = b_hh[2 * H_ + j1];

    float hj0 = 0.0f, hj1 = 0.0f;
    uint32_t ver  = 1;    // ver 1 == initial zero state, lives in slot 1
    uint32_t dead = 0;    // leader watchdog state (wave-uniform)

    // publish initial tagged packed state (bf16 zeros == 0 bits)
    if (lane == 0)
        __hip_atomic_store(&h_buf[(ver & 1) * 256 + q], (uint64_t)ver << 32,
                           __ATOMIC_RELAXED, __HIP_MEMORY_SCOPE_AGENT);

    float xv[16];     // current step's visit row (prefetched)
    float iv = 0.0f;  // current step's interval

    for (int b = 0; b < B_; ++b) {
        const int L = lens[b];
        if (L > 0) {
            iv = intervals[b * T_];
            const float* vrow = visit_emb + (size_t)(b * T_) * V_;
            #pragma unroll
            for (int u = 0; u < 16; ++u) xv[u] = vrow[lane + 64 * u];
        }
        for (int t = 0; t < L; ++t) {
            // ---- x-side dots from prefetched row (h-independent) --------
            const float xt = fmaf(iv, wt, bt);
            float ar0 = ir0[16] * xt, ar1 = ir1[16] * xt;
            float az0 = iz0[16] * xt, az1 = iz1[16] * xt;
            float xn0 = in0[16] * xt, xn1 = in1[16] * xt;
            #pragma unroll
            for (int u = 0; u < 16; ++u) {
                ar0 = fmaf(ir0[u], xv[u], ar0);
                ar1 = fmaf(ir1[u], xv[u], ar1);
                az0 = fmaf(iz0[u], xv[u], az0);
                az1 = fmaf(iz1[u], xv[u], az1);
                xn0 = fmaf(in0[u], xv[u], xn0);
                xn1 = fmaf(in1[u], xv[u], xn1);
            }
            // ---- prefetch next step's x row (hides under the poll) ------
            if (t + 1 < L) {
                iv = intervals[b * T_ + t + 1];
                const float* vrow = visit_emb + (size_t)(b * T_ + t + 1) * V_;
                #pragma unroll
                for (int u = 0; u < 16; ++u) xv[u] = vrow[lane + 64 * u];
            }

            // ---- leader wave: poll 256 packed words, broadcast LDS ------
            if (wave == 0) {
                const uint64_t* src = h_buf + (ver & 1) * 256;
                uint64_t w[4];
                if (!dead) {
                    uint32_t tries = 0;
                    bool ok;
                    do {
                        ok = true;
                        #pragma unroll
                        for (int u = 0; u < 4; ++u) {
                            w[u] = __hip_atomic_load(&src[lane + 64 * u],
                                                     __ATOMIC_RELAXED,
                                                     __HIP_MEMORY_SCOPE_AGENT);
                            ok = ok && ((uint32_t)(w[u] >> 32) == ver);
                        }
                        if (++tries > (1u << 21)) { dead = 1; break; }
                    } while (!__all(ok));
                } else {
                    #pragma unroll
                    for (int u = 0; u < 4; ++u)
                        w[u] = __hip_atomic_load(&src[lane + 64 * u],
                                                 __ATOMIC_RELAXED,
                                                 __HIP_MEMORY_SCOPE_AGENT);
                }
                #pragma unroll
                for (int u = 0; u < 4; ++u) {
                    const uint32_t d = (uint32_t)w[u];
                    hs2[lane + 64 * u] =
                        make_float2(bf16_to_f32_(d & 0xFFFFu),
                                    bf16_to_f32_(d >> 16));
                }
            }
            __syncthreads();

            float h[8];
            #pragma unroll
            for (int u = 0; u < 8; ++u) h[u] = hs[lane + 64 * u];

            // ---- h-side dots; r/z merged with x-side, n kept split ------
            float hn0 = 0.0f, hn1 = 0.0f;
            #pragma unroll
            for (int u = 0; u < 8; ++u) {
                ar0 = fmaf(wr0[u], h[u], ar0);
                ar1 = fmaf(wr1[u], h[u], ar1);
                az0 = fmaf(wz0[u], h[u], az0);
                az1 = fmaf(wz1[u], h[u], az1);
                hn0 = fmaf(wn0[u], h[u], hn0);
                hn1 = fmaf(wn1[u], h[u], hn1);
            }
            #pragma unroll
            for (int m = 1; m < 64; m <<= 1) {
                ar0 += __shfl_xor(ar0, m, 64);
                ar1 += __shfl_xor(ar1, m, 64);
                az0 += __shfl_xor(az0, m, 64);
                az1 += __shfl_xor(az1, m, 64);
                xn0 += __shfl_xor(xn0, m, 64);
                xn1 += __shfl_xor(xn1, m, 64);
                hn0 += __shfl_xor(hn0, m, 64);
                hn1 += __shfl_xor(hn1, m, 64);
            }

            const float r0 = sigmoidf_(ar0 + bir0 + bhr0);
            const float r1 = sigmoidf_(ar1 + bir1 + bhr1);
            const float z0 = sigmoidf_(az0 + biz0 + bhz0);
            const float z1 = sigmoidf_(az1 + biz1 + bhz1);
            const float n0 = tanhf_(xn0 + bin0 + r0 * (hn0 + bhn0));
            const float n1 = tanhf_(xn1 + bin1 + r1 * (hn1 + bhn1));
            hj0 = (1.0f - z0) * n0 + z0 * hj0;
            hj1 = (1.0f - z1) * n1 + z1 * hj1;

            // ---- publish ONE tagged packed word per wave ----------------
            ++ver;
            if (lane == 0) {
                const uint32_t packed =
                    bf16_rn_(hj0) | (bf16_rn_(hj1) << 16);
                __hip_atomic_store(&h_buf[(ver & 1) * 256 + q],
                    ((uint64_t)ver << 32) | (uint64_t)packed,
                    __ATOMIC_RELAXED, __HIP_MEMORY_SCOPE_AGENT);
            }
        }
        // out[b] = h after sample b's (possibly empty) segment
        if (lane < 2) out[b * H_ + j0 + lane] = (lane == 0) ? hj0 : hj1;
    }
}

// ---------------------------------------------------------------------------
extern "C" void kernel_launch(void* const* d_in, const int* in_sizes, int n_in,
                              void* d_out, int out_size, void* d_ws, size_t ws_size,
                              hipStream_t stream)
{
    const float* visit_emb = (const float*)d_in[0];
    const float* intervals = (const float*)d_in[1];
    const float* W_time    = (const float*)d_in[2];
    const float* b_time    = (const float*)d_in[3];
    const float* W_ih      = (const float*)d_in[4];
    const float* W_hh      = (const float*)d_in[5];
    const float* b_ih      = (const float*)d_in[6];
    const float* b_hh      = (const float*)d_in[7];
    const int*   lens      = (const int*)d_in[8];
    float*       out       = (float*)d_out;

    // workspace: packed tagged h exchange (2 x 256 x u64 = 4 KiB)
    uint64_t* h_buf = (uint64_t*)d_ws;

    gru_fused<<<64, 256, 0, stream>>>(visit_emb, intervals, W_time, b_time,
                                      W_ih, W_hh, b_ih, b_hh, lens, h_buf, out);
}

// Round 10
// 7418.505 us; speedup vs baseline: 2.2875x; 1.1595x over previous
//
#include <hip/hip_runtime.h>
#include <stdint.h>

#define B_   128
#define T_   64
#define V_   1024
#define TS_  64
#define H_   512
#define K_   (V_ + TS_)   // 1088

// ---------------------------------------------------------------------------
// Fused time-aware GRU scan, round 10.
//
// Structure = round 9 (best: 8.60ms / 2.13us/step): 64 WGs x 256 threads
// (4 waves), wave q = blk*4+w owns h[2q],h[2q+1]; wave 0 polls the packed
// bf16-tagged exchange and broadcasts via LDS + one __syncthreads.
//
// Evidence ledger: r2->r6 4x fewer pollers +27%; r7 backoff -7%; r8 masks+
// replicas -89%; r9 half stores+half sweep +4%. All traffic knobs dead =>
// step time is (clock-scaled) SERIAL CYCLES: store-vis + detect + barrier +
// compute. At 6% VALU the DPM governor runs ~1.2GHz (5x slower first
// dispatch while ramping), doubling every cycle's cost.
//
// r10: cut cycles on the chain, change nothing else.
//   1. DPP wave reduction replaces the 8-value x 6-round __shfl_xor
//      butterfly: 48 ds_swizzle ops (6 dependent LDS-latency rounds,
//      ~500-700cyc) -> 48 pipelined VALU DPP adds (~120cyc) + readlane.
//      Gates/recurrence become wave-uniform (identical math).
//   2. Leader issues its first poll sweep BEFORE the x-dots; the tag
//      check's waitcnt then overlaps x-dot FMAs with the LLC round-trip
//      (compiler emits vmcnt(16) since prefetches are younger).
//
// Protocol (unchanged from r9): packed tagged u64 per wave
// (ver<<32)|(bf16(hj1)<<16)|bf16(hj0); agent-relaxed store/load; leader
// sweeps 4 words/lane over 256; bounded-spin watchdog (2^21) => protocol
// bugs end as fast absmax-fails, not dead containers. Safety induction:
// tag v+1 only stored after sync(v); sync(v) needs leader observed all
// tags v; any tag v postdates its WG's reads of slot (v+1)&1 for v-1.
//
// Masked steps (t >= lens[b]) skipped; chain = sum(lens) ~ 4032 steps.
// Workspace: 2 slots x 256 x u64 = 4KB. Poison tag 0xAAAAAAAA != any ver.
// ---------------------------------------------------------------------------

__device__ __forceinline__ float sigmoidf_(float x) {
    return 1.0f / (1.0f + __expf(-x));
}
__device__ __forceinline__ float tanhf_(float x) {
    x = fminf(fmaxf(x, -15.0f), 15.0f);
    const float e = __expf(2.0f * x);
    return (e - 1.0f) / (e + 1.0f);
}
__device__ __forceinline__ uint32_t bf16_rn_(float f) {
    uint32_t u = __float_as_uint(f);
    u += 0x7FFFu + ((u >> 16) & 1u);   // round-to-nearest-even
    return u >> 16;
}
__device__ __forceinline__ float bf16_to_f32_(uint32_t b) {
    return __uint_as_float(b << 16);
}

// classic GCN DPP full-wave sum: row_shr 1/2/4/8, row_bcast 15/31; total
// lands in lane 63; readlane broadcasts. old=0 + bound_ctrl=1 => masked /
// invalid lanes contribute +0.
template <int CTRL, int RM, int BM>
__device__ __forceinline__ float dpp_add_(float a) {
    const int x = __builtin_amdgcn_update_dpp(
        0, __float_as_int(a), CTRL, RM, BM, true);
    return a + __int_as_float(x);
}
__device__ __forceinline__ float wave_sum_(float a) {
    a = dpp_add_<0x111, 0xF, 0xF>(a);   // row_shr:1
    a = dpp_add_<0x112, 0xF, 0xF>(a);   // row_shr:2
    a = dpp_add_<0x114, 0xF, 0xE>(a);   // row_shr:4
    a = dpp_add_<0x118, 0xF, 0xC>(a);   // row_shr:8
    a = dpp_add_<0x142, 0xA, 0xF>(a);   // row_bcast:15
    a = dpp_add_<0x143, 0xC, 0xF>(a);   // row_bcast:31
    return __int_as_float(__builtin_amdgcn_readlane(__float_as_int(a), 63));
}

__global__ __launch_bounds__(256, 1) void gru_fused(
    const float* __restrict__ visit_emb, const float* __restrict__ intervals,
    const float* __restrict__ W_time, const float* __restrict__ b_time,
    const float* __restrict__ W_ih, const float* __restrict__ W_hh,
    const float* __restrict__ b_ih, const float* __restrict__ b_hh,
    const int* __restrict__ lens,
    uint64_t* h_buf /* [2 slot][256] tagged packed */,
    float* __restrict__ out)
{
    const int lane = threadIdx.x & 63;
    const int wave = threadIdx.x >> 6;        // 0..3
    const int q    = blockIdx.x * 4 + wave;   // 0..255 global wave id
    const int j0   = q * 2;
    const int j1   = j0 + 1;

    __shared__ float2 hs2[256];               // unpacked h pairs (fp32)
    float* hs = (float*)hs2;                  // alias: hs[512]

    // ---- register-resident W_hh rows (k = lane + 64u) -------------------
    float wr0[8], wr1[8], wz0[8], wz1[8], wn0[8], wn1[8];
    #pragma unroll
    for (int u = 0; u < 8; ++u) {
        const int k = lane + 64 * u;
        wr0[u] = W_hh[(size_t)j0 * H_ + k];
        wr1[u] = W_hh[(size_t)j1 * H_ + k];
        wz0[u] = W_hh[(size_t)(H_ + j0) * H_ + k];
        wz1[u] = W_hh[(size_t)(H_ + j1) * H_ + k];
        wn0[u] = W_hh[(size_t)(2 * H_ + j0) * H_ + k];
        wn1[u] = W_hh[(size_t)(2 * H_ + j1) * H_ + k];
    }
    // ---- W_ih rows: u<16 visit part, u==16 time part --------------------
    float ir0[17], ir1[17], iz0[17], iz1[17], in0[17], in1[17];
    #pragma unroll
    for (int u = 0; u < 16; ++u) {
        const int k = lane + 64 * u;
        ir0[u] = W_ih[(size_t)j0 * K_ + k];
        ir1[u] = W_ih[(size_t)j1 * K_ + k];
        iz0[u] = W_ih[(size_t)(H_ + j0) * K_ + k];
        iz1[u] = W_ih[(size_t)(H_ + j1) * K_ + k];
        in0[u] = W_ih[(size_t)(2 * H_ + j0) * K_ + k];
        in1[u] = W_ih[(size_t)(2 * H_ + j1) * K_ + k];
    }
    ir0[16] = W_ih[(size_t)j0 * K_ + V_ + lane];
    ir1[16] = W_ih[(size_t)j1 * K_ + V_ + lane];
    iz0[16] = W_ih[(size_t)(H_ + j0) * K_ + V_ + lane];
    iz1[16] = W_ih[(size_t)(H_ + j1) * K_ + V_ + lane];
    in0[16] = W_ih[(size_t)(2 * H_ + j0) * K_ + V_ + lane];
    in1[16] = W_ih[(size_t)(2 * H_ + j1) * K_ + V_ + lane];

    const float wt = W_time[lane];
    const float bt = b_time[lane];

    const float bir0 = b_ih[j0],          bir1 = b_ih[j1];
    const float biz0 = b_ih[H_ + j0],     biz1 = b_ih[H_ + j1];
    const float bin0 = b_ih[2 * H_ + j0], bin1 = b_ih[2 * H_ + j1];
    const float bhr0 = b_hh[j0],          bhr1 = b_hh[j1];
    const float bhz0 = b_hh[H_ + j0],     bhz1 = b_hh[H_ + j1];
    const float bhn0 = b_hh[2 * H_ + j0], bhn1 = b_hh[2 * H_ + j1];

    float hj0 = 0.0f, hj1 = 0.0f;             // wave-uniform state
    uint32_t ver  = 1;    // ver 1 == initial zero state, lives in slot 1
    uint32_t dead = 0;    // leader watchdog state (wave-uniform)

    // publish initial tagged packed state (bf16 zeros == 0 bits)
    if (lane == 0)
        __hip_atomic_store(&h_buf[(ver & 1) * 256 + q], (uint64_t)ver << 32,
                           __ATOMIC_RELAXED, __HIP_MEMORY_SCOPE_AGENT);

    float xv[16];     // current step's visit row (prefetched)
    float iv = 0.0f;  // current step's interval

    for (int b = 0; b < B_; ++b) {
        const int L = lens[b];
        if (L > 0) {
            iv = intervals[b * T_];
            const float* vrow = visit_emb + (size_t)(b * T_) * V_;
            #pragma unroll
            for (int u = 0; u < 16; ++u) xv[u] = vrow[lane + 64 * u];
        }
        for (int t = 0; t < L; ++t) {
            // ---- leader: ISSUE first sweep before x-dots ----------------
            const uint64_t* src = h_buf + (ver & 1) * 256;
            uint64_t w[4];
            if (wave == 0) {
                #pragma unroll
                for (int u = 0; u < 4; ++u)
                    w[u] = __hip_atomic_load(&src[lane + 64 * u],
                                             __ATOMIC_RELAXED,
                                             __HIP_MEMORY_SCOPE_AGENT);
            }

            // ---- x-side dots (h-independent; overlap the sweep) ---------
            const float xt = fmaf(iv, wt, bt);
            float ar0 = ir0[16] * xt, ar1 = ir1[16] * xt;
            float az0 = iz0[16] * xt, az1 = iz1[16] * xt;
            float xn0 = in0[16] * xt, xn1 = in1[16] * xt;
            #pragma unroll
            for (int u = 0; u < 16; ++u) {
                ar0 = fmaf(ir0[u], xv[u], ar0);
                ar1 = fmaf(ir1[u], xv[u], ar1);
                az0 = fmaf(iz0[u], xv[u], az0);
                az1 = fmaf(iz1[u], xv[u], az1);
                xn0 = fmaf(in0[u], xv[u], xn0);
                xn1 = fmaf(in1[u], xv[u], xn1);
            }
            // ---- prefetch next step's x row (in flight across barrier) --
            if (t + 1 < L) {
                iv = intervals[b * T_ + t + 1];
                const float* vrow = visit_emb + (size_t)(b * T_ + t + 1) * V_;
                #pragma unroll
                for (int u = 0; u < 16; ++u) xv[u] = vrow[lane + 64 * u];
            }

            // ---- leader: check tags (waitcnt lands here), retry, LDS ----
            if (wave == 0) {
                if (!dead) {
                    bool ok = true;
                    #pragma unroll
                    for (int u = 0; u < 4; ++u)
                        ok = ok && ((uint32_t)(w[u] >> 32) == ver);
                    uint32_t tries = 0;
                    while (!__all(ok)) {
                        if (++tries > (1u << 21)) { dead = 1; break; }
                        ok = true;
                        #pragma unroll
                        for (int u = 0; u < 4; ++u) {
                            w[u] = __hip_atomic_load(&src[lane + 64 * u],
                                                     __ATOMIC_RELAXED,
                                                     __HIP_MEMORY_SCOPE_AGENT);
                            ok = ok && ((uint32_t)(w[u] >> 32) == ver);
                        }
                    }
                }
                #pragma unroll
                for (int u = 0; u < 4; ++u) {
                    const uint32_t d = (uint32_t)w[u];
                    hs2[lane + 64 * u] =
                        make_float2(bf16_to_f32_(d & 0xFFFFu),
                                    bf16_to_f32_(d >> 16));
                }
            }
            __syncthreads();

            float h[8];
            #pragma unroll
            for (int u = 0; u < 8; ++u) h[u] = hs[lane + 64 * u];

            // ---- h-side dots; r/z merged with x-side, n kept split ------
            float hn0 = 0.0f, hn1 = 0.0f;
            #pragma unroll
            for (int u = 0; u < 8; ++u) {
                ar0 = fmaf(wr0[u], h[u], ar0);
                ar1 = fmaf(wr1[u], h[u], ar1);
                az0 = fmaf(wz0[u], h[u], az0);
                az1 = fmaf(wz1[u], h[u], az1);
                hn0 = fmaf(wn0[u], h[u], hn0);
                hn1 = fmaf(wn1[u], h[u], hn1);
            }

            // ---- 8 pipelined DPP wave sums (VALU, no LDS rounds) --------
            const float sr0 = wave_sum_(ar0), sr1 = wave_sum_(ar1);
            const float sz0 = wave_sum_(az0), sz1 = wave_sum_(az1);
            const float sx0 = wave_sum_(xn0), sx1 = wave_sum_(xn1);
            const float sh0 = wave_sum_(hn0), sh1 = wave_sum_(hn1);

            // ---- gates & recurrence (wave-uniform) ----------------------
            const float r0 = sigmoidf_(sr0 + bir0 + bhr0);
            const float r1 = sigmoidf_(sr1 + bir1 + bhr1);
            const float z0 = sigmoidf_(sz0 + biz0 + bhz0);
            const float z1 = sigmoidf_(sz1 + biz1 + bhz1);
            const float n0 = tanhf_(sx0 + bin0 + r0 * (sh0 + bhn0));
            const float n1 = tanhf_(sx1 + bin1 + r1 * (sh1 + bhn1));
            hj0 = (1.0f - z0) * n0 + z0 * hj0;
            hj1 = (1.0f - z1) * n1 + z1 * hj1;

            // ---- publish ONE tagged packed word per wave ----------------
            ++ver;
            if (lane == 0) {
                const uint32_t packed =
                    bf16_rn_(hj0) | (bf16_rn_(hj1) << 16);
                __hip_atomic_store(&h_buf[(ver & 1) * 256 + q],
                    ((uint64_t)ver << 32) | (uint64_t)packed,
                    __ATOMIC_RELAXED, __HIP_MEMORY_SCOPE_AGENT);
            }
        }
        // out[b] = h after sample b's (possibly empty) segment
        if (lane < 2) out[b * H_ + j0 + lane] = (lane == 0) ? hj0 : hj1;
    }
}

// ---------------------------------------------------------------------------
extern "C" void kernel_launch(void* const* d_in, const int* in_sizes, int n_in,
                              void* d_out, int out_size, void* d_ws, size_t ws_size,
                              hipStream_t stream)
{
    const float* visit_emb = (const float*)d_in[0];
    const float* intervals = (const float*)d_in[1];
    const float* W_time    = (const float*)d_in[2];
    const float* b_time    = (const float*)d_in[3];
    const float* W_ih      = (const float*)d_in[4];
    const float* W_hh      = (const float*)d_in[5];
    const float* b_ih      = (const float*)d_in[6];
    const float* b_hh      = (const float*)d_in[7];
    const int*   lens      = (const int*)d_in[8];
    float*       out       = (float*)d_out;

    // workspace: packed tagged h exchange (2 x 256 x u64 = 4 KiB)
    uint64_t* h_buf = (uint64_t*)d_ws;

    gru_fused<<<64, 256, 0, stream>>>(visit_emb, intervals, W_time, b_time,
                                      W_ih, W_hh, b_ih, b_hh, lens, h_buf, out);
}